// Round 11
// baseline (2649.807 us; speedup 1.0000x reference)
//
#include <hip/hip_runtime.h>

// GRU LM: L=2, B=64, S=64, E=H=1024, V=32000. All ref math fp32; we use bf16 MFMA.
#define SBV 131072000    // S*B*V logits element count

typedef __bf16 bf16x8 __attribute__((ext_vector_type(8)));
typedef float  f32x4  __attribute__((ext_vector_type(4)));
typedef unsigned short u16;

__device__ __forceinline__ u16 f2bf(float f) {
  union { float f; unsigned u; } c; c.f = f;
  return (u16)((c.u + 0x7fffu + ((c.u >> 16) & 1u)) >> 16);  // RNE
}
__device__ __forceinline__ float sigm(float x) { return 1.f / (1.f + __expf(-x)); }
__device__ __forceinline__ float tanh_f(float x) { return 2.f / (1.f + __expf(-2.f * x)) - 1.f; }

// ---------------- prep kernels ----------------

__global__ void k_cvtv(const float* __restrict__ src, u16* __restrict__ dst, int n4) {
  const float4* s4 = (const float4*)src;
  ushort4* d4 = (ushort4*)dst;
  for (int i = blockIdx.x * blockDim.x + threadIdx.x; i < n4; i += gridDim.x * blockDim.x) {
    float4 v = s4[i];
    ushort4 o; o.x = f2bf(v.x); o.y = f2bf(v.y); o.z = f2bf(v.z); o.w = f2bf(v.w);
    d4[i] = o;
  }
}

__global__ void k_pack3(const float* __restrict__ sx, const float* __restrict__ sz,
                        const float* __restrict__ sh, int srcOff, u16* __restrict__ dst) {
  int i = blockIdx.x * blockDim.x + threadIdx.x;  // over 3M/4 float4s
  if (i >= 786432) return;
  int g = i >> 18;            // 0..2 gate
  int r4 = i & 262143;        // float4 index within 1M-elem matrix
  const float* s = (g == 0 ? sx : (g == 1 ? sz : sh)) + srcOff;
  float4 v = ((const float4*)s)[r4];
  ushort4 o; o.x = f2bf(v.x); o.y = f2bf(v.y); o.z = f2bf(v.z); o.w = f2bf(v.w);
  ((ushort4*)dst)[i] = o;
}

__global__ void k_embed(const int* __restrict__ idx, const float* __restrict__ emb,
                        u16* __restrict__ xe) {
  int i = blockIdx.x * blockDim.x + threadIdx.x;  // over 4096*256 float4s
  if (i >= 1048576) return;
  int row = i >> 8, k4 = i & 255;
  int e = idx[row];
  float4 v = ((const float4*)emb)[(size_t)e * 256 + k4];
  ushort4 o; o.x = f2bf(v.x); o.y = f2bf(v.y); o.z = f2bf(v.z); o.w = f2bf(v.w);
  ((ushort4*)xe)[i] = o;
}

// ---------------- GEMM: C[M,N] = A[M,K] @ B[N,K]^T, bf16 in / fp32 out (X0 only) ----------------
__global__ __launch_bounds__(256) void gemm_bt(const u16* __restrict__ A, const u16* __restrict__ Bm,
                                               float* __restrict__ C, int M, int N, int K, int mtiles) {
  __shared__ u16 As[128 * 32];
  __shared__ u16 Bs[128 * 32];
  const int tid = threadIdx.x;
  const int bm = blockIdx.x % mtiles, bn = blockIdx.x / mtiles;
  const int m0 = bm * 128, n0 = bn * 128;
  const int lane = tid & 63, w = tid >> 6, wm = w & 1, wn = w >> 1;
  const int la = lane & 15, lk = lane >> 4;
  const int srow = tid >> 2, sk = (tid & 3) * 8;
  f32x4 acc[4][4] = {};
  for (int kt = 0; kt < K; kt += 32) {
    const u16* srcA0 = A + (size_t)(m0 + srow) * K + kt + sk;
    const u16* srcA1 = A + (size_t)(m0 + srow + 64) * K + kt + sk;
    const u16* srcB0 = Bm + (size_t)(n0 + srow) * K + kt + sk;
    const u16* srcB1 = Bm + (size_t)(n0 + srow + 64) * K + kt + sk;
    __builtin_amdgcn_global_load_lds((const __attribute__((address_space(1))) void*)srcA0,
        (__attribute__((address_space(3))) void*)((char*)As + tid * 16), 16, 0, 0);
    __builtin_amdgcn_global_load_lds((const __attribute__((address_space(1))) void*)srcA1,
        (__attribute__((address_space(3))) void*)((char*)As + 4096 + tid * 16), 16, 0, 0);
    __builtin_amdgcn_global_load_lds((const __attribute__((address_space(1))) void*)srcB0,
        (__attribute__((address_space(3))) void*)((char*)Bs + tid * 16), 16, 0, 0);
    __builtin_amdgcn_global_load_lds((const __attribute__((address_space(1))) void*)srcB1,
        (__attribute__((address_space(3))) void*)((char*)Bs + 4096 + tid * 16), 16, 0, 0);
    __syncthreads();
    bf16x8 av[4], bv[4];
    #pragma unroll
    for (int m = 0; m < 4; ++m)
      av[m] = *(const bf16x8*)(As + (wm * 64 + m * 16 + la) * 32 + lk * 8);
    #pragma unroll
    for (int n = 0; n < 4; ++n)
      bv[n] = *(const bf16x8*)(Bs + (wn * 64 + n * 16 + la) * 32 + lk * 8);
    #pragma unroll
    for (int m = 0; m < 4; ++m)
      #pragma unroll
      for (int n = 0; n < 4; ++n)
        acc[m][n] = __builtin_amdgcn_mfma_f32_16x16x32_bf16(av[m], bv[n], acc[m][n], 0, 0, 0);
    __syncthreads();
  }
  #pragma unroll
  for (int n = 0; n < 4; ++n) {
    const int gc = n0 + wn * 64 + n * 16 + la;
    #pragma unroll
    for (int m = 0; m < 4; ++m) {
      const int gr0 = m0 + wm * 64 + m * 16 + lk * 4;
      #pragma unroll
      for (int r = 0; r < 4; ++r)
        C[(size_t)(gr0 + r) * N + gc] = acc[m][n][r];
    }
  }
}

// ---------------- sync: per-phase ring counters ----------------
// Arrival: tid0 relaxed agent atomicAdd on cnt[group][phase] (fresh word per phase:
// no reuse, no min-scan; relaxed -> no wbl2). Wait: each wave's lane 0 polls the ONE
// dword until ==64, wave proceeds immediately (no cross-wave sync needed: LDS weights
// are read-only, state is per-thread, RH/Hseq visibility is via the counter itself).

__device__ __forceinline__ void waitc1(const unsigned* wptr, unsigned need) {
  if (!need) return;
  unsigned g = 0;
  while (true) {
    unsigned v = need;
    if ((threadIdx.x & 63) == 0)
      asm volatile("global_load_dword %0, %1, off sc1\ns_waitcnt vmcnt(0)"
                   : "=v"(v) : "v"(wptr) : "memory");
    if (__all(v >= need)) break;
    __builtin_amdgcn_s_sleep(1);
    if (++g > 400000u) break;   // hang guard (~0.15s)
  }
}

__device__ __forceinline__ void waitc2(const unsigned* w0, unsigned n0,
                                       const unsigned* w1, unsigned n1) {
  unsigned g = 0;
  while (true) {
    const int l = threadIdx.x & 63;
    bool ok = true;
    if (l < 2) {
      const unsigned* p = l ? w1 : w0;
      const unsigned need = l ? n1 : n0;
      unsigned v;
      asm volatile("global_load_dword %0, %1, off sc1\ns_waitcnt vmcnt(0)"
                   : "=v"(v) : "v"(p) : "memory");
      ok = (need == 0) || (v >= need);
    }
    if (__all(ok)) break;
    __builtin_amdgcn_s_sleep(1);
    if (++g > 400000u) break;
  }
}

__device__ __forceinline__ void arrivec(unsigned* wptr, int tid) {
  asm volatile("s_waitcnt vmcnt(0)" ::: "memory");   // per-wave: my sc1 stores at LLC
  __syncthreads();                                    // all waves drained
  if (tid == 0)
    __hip_atomic_fetch_add(wptr, 1u, __ATOMIC_RELAXED, __HIP_MEMORY_SCOPE_AGENT);
}

// ---------------- fused persistent kernel: recurrence + flag-chasing decoder ----------------
// Blocks 0..127: weight-stationary GRU recurrence. Blocks 128..252: decoder workers.
// Coherence: sc1 write-through stores; plain cached reads of write-once data strictly
// after counter; ONE agent-acquire fence at kernel entry (graph-replay staleness).

__global__ __launch_bounds__(256) void k_fused(
    const u16* __restrict__ hinitb,    // [2][64][1024] bf16 of initial hidden
    const float* __restrict__ hidden,  // [2][64][1024] fp32
    const float* __restrict__ X0,      // [64][64][3072] layer-0 x-projections
    const u16* __restrict__ Ucat0, const u16* __restrict__ Ucat1,  // [3072][1024] {Ur|Uz|Uh}
    const u16* __restrict__ Wcat1,                                  // [3072][1024] {Wx|Wz|Wh} layer1
    const float* __restrict__ br, const float* __restrict__ bz, const float* __restrict__ bh,
    u16* __restrict__ H0seq, u16* __restrict__ H1seq,  // [64][64][1024] bf16 hidden per step
    u16* __restrict__ RH0, u16* __restrict__ RH1,      // [64][64][1024] bf16 r*h per step
    const u16* __restrict__ decWb,     // [32000][1024] bf16 decoder weights
    const float* __restrict__ decb,    // [32000]
    float* __restrict__ out,           // logits [64*64][32000]; hfinal at out+SBV
    unsigned* cnt) {                   // ring counters: [2][132]
  extern __shared__ char sW[];        // 96KB (recurrence blocks): 3 x [16][1024] swizzled
  const int tid = threadIdx.x, bid = blockIdx.x;
  const int lane = tid & 63, w = tid >> 6;
  const int la = lane & 15, lk = lane >> 4;

  // drop stale L1/L2 lines from previous graph replay (ONCE per launch, all blocks)
  __builtin_amdgcn_fence(__ATOMIC_ACQUIRE, "agent");

  if (bid >= 128) {
    // ================= decoder worker =================
    const int d = bid - 128;          // 0..124
    const int c0 = d * 256 + w * 64;  // wave's 64-col strip
    const unsigned* cL1 = cnt + 132;
    float bb[4];
    #pragma unroll
    for (int nf = 0; nf < 4; ++nf) bb[nf] = decb[c0 + nf * 16 + la];
    const u16* Bp[4];
    #pragma unroll
    for (int nf = 0; nf < 4; ++nf)
      Bp[nf] = decWb + (size_t)(c0 + nf * 16 + la) * 1024 + lk * 8;
    for (int t = 0; t < 64; ++t) {
      waitc1(cL1 + 2 * t + 2, 64u);            // H1seq[t] complete
      const u16* Ab = H1seq + (size_t)t * 65536;
      const u16* Ap[4];
      #pragma unroll
      for (int mf = 0; mf < 4; ++mf) Ap[mf] = Ab + (mf * 16 + la) * 1024 + lk * 8;
      f32x4 acc[4][4] = {};
      #pragma unroll 4
      for (int ks = 0; ks < 32; ++ks) {
        bf16x8 av[4], bv[4];
        #pragma unroll
        for (int mf = 0; mf < 4; ++mf) av[mf] = *(const bf16x8*)(Ap[mf] + ks * 32);
        #pragma unroll
        for (int nf = 0; nf < 4; ++nf) bv[nf] = *(const bf16x8*)(Bp[nf] + ks * 32);
        #pragma unroll
        for (int mf = 0; mf < 4; ++mf)
          #pragma unroll
          for (int nf = 0; nf < 4; ++nf)
            acc[mf][nf] = __builtin_amdgcn_mfma_f32_16x16x32_bf16(av[mf], bv[nf], acc[mf][nf], 0, 0, 0);
      }
      #pragma unroll
      for (int mf = 0; mf < 4; ++mf)
        #pragma unroll
        for (int nf = 0; nf < 4; ++nf) {
          const size_t rb = (size_t)(t * 64 + mf * 16 + lk * 4) * 32000 + c0 + nf * 16 + la;
          #pragma unroll
          for (int r = 0; r < 4; ++r)
            out[rb + (size_t)r * 32000] = acc[mf][nf][r] + bb[nf];
        }
    }
    return;
  }

  // ================= recurrence block =================
  const int layer = bid >> 6, jb = bid & 63, j0 = jb * 16;
  const int jl = j0 + la;             // this lane's output col (C/D: col = lane&15)
  const int row0 = w * 16;            // wave's 16 batch rows
  const u16* Ucat = layer ? Ucat1 : Ucat0;
  u16* Hseq = layer ? H1seq : H0seq;
  u16* RHl = layer ? RH1 : RH0;
  const u16* hinit = hinitb + layer * 65536;
  unsigned* cSelf = cnt + layer * 132;
  const unsigned* cL0 = cnt;
  float* houtf = out + (size_t)SBV;

  // ---- stage U weight slice into LDS (once): 6144 16B-chunks / 256 thr = 24 each ----
  const int xorv = (la & 7) << 4;
  for (int i = 0; i < 24; ++i) {
    int c = i * 256 + tid;                       // 0..6143
    int g = c >> 11, rem = c & 2047;             // 2048 chunks per gate
    int urow = rem >> 7, kc = rem & 127;
    uint4 v = *(const uint4*)(Ucat + ((size_t)((g << 10) + j0 + urow)) * 1024 + kc * 8);
    *(uint4*)(sW + (g << 15) + urow * 2048 + ((kc * 16) ^ ((urow & 7) << 4))) = v;
  }
  __syncthreads();
  const char* sWla = sW + la * 2048;             // per-lane weight row base

  float h_reg[4], z_reg[4];
  #pragma unroll
  for (int r = 0; r < 4; ++r)
    h_reg[r] = hidden[layer * 65536 + (row0 + lk * 4 + r) * 1024 + jl];
  const float bR = br[layer * 1024 + jl], bZ = bz[layer * 1024 + jl], bH = bh[layer * 1024 + jl];

  // L1 W-stream row bases (B-operand: row = col j0+la), plain loads -> L2-resident slice
  const u16* WrR = Wcat1 + (size_t)(j0 + la) * 1024 + lk * 8;
  const u16* WrZ = WrR + (size_t)1024 * 1024;
  const u16* WrH = WrR + (size_t)2048 * 1024;

  for (int t = 0; t < 64; ++t) {
    // ================= phase A: r,z gates =================
    if (layer == 0) waitc1(cSelf + 2 * t, t ? 64u : 0u);
    else            waitc2(cSelf + 2 * t, t ? 64u : 0u, cL0 + 2 * t + 2, 64u);
    const u16* hsrc = (t == 0) ? hinit : (Hseq + (size_t)(t - 1) * 65536);
    const u16* ap = hsrc + (size_t)(row0 + la) * 1024 + lk * 8;
    f32x4 accR = {0.f, 0.f, 0.f, 0.f}, accZ = {0.f, 0.f, 0.f, 0.f};
    if (layer == 0) {
      #pragma unroll 16
      for (int ks = 0; ks < 32; ++ks) {
        const int kx = (ks * 64 + lk * 16) ^ xorv;
        bf16x8 a = *(const bf16x8*)(ap + ks * 32);
        accR = __builtin_amdgcn_mfma_f32_16x16x32_bf16(a, *(const bf16x8*)(sWla + kx), accR, 0, 0, 0);
        accZ = __builtin_amdgcn_mfma_f32_16x16x32_bf16(a, *(const bf16x8*)(sWla + 32768 + kx), accZ, 0, 0, 0);
      }
    } else {
      const u16* xp = H0seq + (size_t)t * 65536 + (size_t)(row0 + la) * 1024 + lk * 8;
      #pragma unroll 8
      for (int ks = 0; ks < 32; ++ks) {
        const int kx = (ks * 64 + lk * 16) ^ xorv;
        bf16x8 a = *(const bf16x8*)(ap + ks * 32);
        bf16x8 x = *(const bf16x8*)(xp + ks * 32);
        accR = __builtin_amdgcn_mfma_f32_16x16x32_bf16(a, *(const bf16x8*)(sWla + kx), accR, 0, 0, 0);
        accZ = __builtin_amdgcn_mfma_f32_16x16x32_bf16(a, *(const bf16x8*)(sWla + 32768 + kx), accZ, 0, 0, 0);
        accR = __builtin_amdgcn_mfma_f32_16x16x32_bf16(x, *(const bf16x8*)(WrR + ks * 32), accR, 0, 0, 0);
        accZ = __builtin_amdgcn_mfma_f32_16x16x32_bf16(x, *(const bf16x8*)(WrZ + ks * 32), accZ, 0, 0, 0);
      }
    }
    #pragma unroll
    for (int r = 0; r < 4; ++r) {
      const int row = row0 + lk * 4 + r;  // C/D: row = (lane>>4)*4 + reg
      float pr = accR[r] + bR, pz = accZ[r] + bZ;
      if (layer == 0) {
        const float* xf = X0 + (size_t)(t * 64 + row) * 3072 + jl;
        pr += xf[0]; pz += xf[1024];
      }
      float rv = sigm(pr);
      z_reg[r] = sigm(pz);
      unsigned v = f2bf(rv * h_reg[r]);
      u16* p = RHl + (size_t)(t * 64 + row) * 1024 + jl;
      asm volatile("global_store_short %0, %1, off sc1" :: "v"(p), "v"(v));
    }
    arrivec(cSelf + 2 * t + 1, tid);
    // ================= phase B: candidate + state update =================
    waitc1(cSelf + 2 * t + 1, 64u);
    const u16* rp = RHl + (size_t)t * 65536 + (size_t)(row0 + la) * 1024 + lk * 8;
    f32x4 accH = {0.f, 0.f, 0.f, 0.f};
    if (layer == 0) {
      #pragma unroll 16
      for (int ks = 0; ks < 32; ++ks) {
        const int kx = (ks * 64 + lk * 16) ^ xorv;
        bf16x8 a = *(const bf16x8*)(rp + ks * 32);
        accH = __builtin_amdgcn_mfma_f32_16x16x32_bf16(a, *(const bf16x8*)(sWla + 65536 + kx), accH, 0, 0, 0);
      }
    } else {
      const u16* xp = H0seq + (size_t)t * 65536 + (size_t)(row0 + la) * 1024 + lk * 8;
      #pragma unroll 8
      for (int ks = 0; ks < 32; ++ks) {
        const int kx = (ks * 64 + lk * 16) ^ xorv;
        bf16x8 a = *(const bf16x8*)(rp + ks * 32);
        bf16x8 x = *(const bf16x8*)(xp + ks * 32);
        accH = __builtin_amdgcn_mfma_f32_16x16x32_bf16(a, *(const bf16x8*)(sWla + 65536 + kx), accH, 0, 0, 0);
        accH = __builtin_amdgcn_mfma_f32_16x16x32_bf16(x, *(const bf16x8*)(WrH + ks * 32), accH, 0, 0, 0);
      }
    }
    #pragma unroll
    for (int r = 0; r < 4; ++r) {
      const int row = row0 + lk * 4 + r;
      float pre = accH[r] + bH;
      if (layer == 0) pre += X0[(size_t)(t * 64 + row) * 3072 + 2048 + jl];
      float hc = tanh_f(pre);
      float hn = h_reg[r] + z_reg[r] * (hc - h_reg[r]);  // (1-z)h + z*hcand
      h_reg[r] = hn;
      unsigned v = f2bf(hn);
      u16* p = Hseq + (size_t)(t * 64 + row) * 1024 + jl;
      asm volatile("global_store_short %0, %1, off sc1" :: "v"(p), "v"(v));
      if (t == 63) houtf[layer * 65536 + row * 1024 + jl] = hn;
    }
    arrivec(cSelf + 2 * t + 2, tid);
  }
}

// ---------------- host launch ----------------
extern "C" void kernel_launch(void* const* d_in, const int* in_sizes, int n_in,
                              void* d_out, int out_size, void* d_ws, size_t ws_size,
                              hipStream_t stream) {
  const int* inputs = (const int*)d_in[0];
  const float* hidden = (const float*)d_in[1];
  const float* emb = (const float*)d_in[2];
  const float* Wx = (const float*)d_in[3];
  const float* Ur = (const float*)d_in[4];
  const float* br = (const float*)d_in[5];
  const float* Wz = (const float*)d_in[6];
  const float* Uz = (const float*)d_in[7];
  const float* bz = (const float*)d_in[8];
  const float* Wh = (const float*)d_in[9];
  const float* Uh = (const float*)d_in[10];
  const float* bh = (const float*)d_in[11];
  const float* decW = (const float*)d_in[12];
  const float* decb = (const float*)d_in[13];
  float* out = (float*)d_out;

  char* ws = (char*)d_ws;
  size_t off = 0;
  auto alloc = [&](size_t bytes) { char* p = ws + off; off += (bytes + 255) & ~(size_t)255; return p; };
  unsigned* cnt = (unsigned*)alloc(4096);     // ring counters [2][132]
  u16* hinitb = (u16*)alloc((size_t)2 * 64 * 1024 * 2);
  u16* xe     = (u16*)alloc((size_t)4096 * 1024 * 2);
  u16* Wcat0b = (u16*)alloc((size_t)3072 * 1024 * 2);
  u16* Wcat1b = (u16*)alloc((size_t)3072 * 1024 * 2);
  u16* Ucat0b = (u16*)alloc((size_t)3072 * 1024 * 2);
  u16* Ucat1b = (u16*)alloc((size_t)3072 * 1024 * 2);
  u16* decWb  = (u16*)alloc((size_t)32000 * 1024 * 2);
  float* X0   = (float*)alloc((size_t)4096 * 3072 * 4);
  u16* H0seq  = (u16*)alloc((size_t)4096 * 1024 * 2);
  u16* H1seq  = (u16*)alloc((size_t)4096 * 1024 * 2);
  u16* RH0    = (u16*)alloc((size_t)4096 * 1024 * 2);
  u16* RH1    = (u16*)alloc((size_t)4096 * 1024 * 2);

  hipMemsetAsync(cnt, 0, 4096, stream);
  k_cvtv<<<128, 256, 0, stream>>>(hidden, hinitb, 32768);
  k_pack3<<<3072, 256, 0, stream>>>(Wx, Wz, Wh, 0, Wcat0b);
  k_pack3<<<3072, 256, 0, stream>>>(Wx, Wz, Wh, 1048576, Wcat1b);
  k_pack3<<<3072, 256, 0, stream>>>(Ur, Uz, Uh, 0, Ucat0b);
  k_pack3<<<3072, 256, 0, stream>>>(Ur, Uz, Uh, 1048576, Ucat1b);
  k_embed<<<4096, 256, 0, stream>>>(inputs, emb, xe);
  k_cvtv<<<4096, 256, 0, stream>>>(decW, decWb, 8192000);

  // layer-0 x-projections for all timesteps: [4096,1024] @ [3072,1024]^T
  gemm_bt<<<768, 256, 0, stream>>>(xe, Wcat0b, X0, 4096, 3072, 1024, 32);

  // fused: weight-stationary recurrence (blocks 0..127) + flag-chasing decoder (128..252)
  (void)hipFuncSetAttribute(reinterpret_cast<const void*>(&k_fused),
                            hipFuncAttributeMaxDynamicSharedMemorySize, 98304);
  k_fused<<<253, 256, 98304, stream>>>(hinitb, hidden, X0, Ucat0b, Ucat1b, Wcat1b,
                                       br, bz, bh, H0seq, H1seq, RH0, RH1,
                                       decWb, decb, out, cnt);
}

// Round 12
// 2484.481 us; speedup vs baseline: 1.0665x; 1.0665x over previous
//
#include <hip/hip_runtime.h>

// GRU LM: L=2, B=64, S=64, E=H=1024, V=32000. All ref math fp32; we use bf16 MFMA.
#define SBV 131072000    // S*B*V logits element count

typedef __bf16 bf16x8 __attribute__((ext_vector_type(8)));
typedef float  f32x4  __attribute__((ext_vector_type(4)));
typedef unsigned short u16;

__device__ __forceinline__ u16 f2bf(float f) {
  union { float f; unsigned u; } c; c.f = f;
  return (u16)((c.u + 0x7fffu + ((c.u >> 16) & 1u)) >> 16);  // RNE
}
__device__ __forceinline__ float sigm(float x) { return 1.f / (1.f + __expf(-x)); }
__device__ __forceinline__ float tanh_f(float x) { return 2.f / (1.f + __expf(-2.f * x)) - 1.f; }

// ---------------- prep kernels ----------------

__global__ void k_cvtv(const float* __restrict__ src, u16* __restrict__ dst, int n4) {
  const float4* s4 = (const float4*)src;
  ushort4* d4 = (ushort4*)dst;
  for (int i = blockIdx.x * blockDim.x + threadIdx.x; i < n4; i += gridDim.x * blockDim.x) {
    float4 v = s4[i];
    ushort4 o; o.x = f2bf(v.x); o.y = f2bf(v.y); o.z = f2bf(v.z); o.w = f2bf(v.w);
    d4[i] = o;
  }
}

__global__ void k_pack3(const float* __restrict__ sx, const float* __restrict__ sz,
                        const float* __restrict__ sh, int srcOff, u16* __restrict__ dst) {
  int i = blockIdx.x * blockDim.x + threadIdx.x;  // over 3M/4 float4s
  if (i >= 786432) return;
  int g = i >> 18;            // 0..2 gate
  int r4 = i & 262143;        // float4 index within 1M-elem matrix
  const float* s = (g == 0 ? sx : (g == 1 ? sz : sh)) + srcOff;
  float4 v = ((const float4*)s)[r4];
  ushort4 o; o.x = f2bf(v.x); o.y = f2bf(v.y); o.z = f2bf(v.z); o.w = f2bf(v.w);
  ((ushort4*)dst)[i] = o;
}

__global__ void k_embed(const int* __restrict__ idx, const float* __restrict__ emb,
                        u16* __restrict__ xe) {
  int i = blockIdx.x * blockDim.x + threadIdx.x;  // over 4096*256 float4s
  if (i >= 1048576) return;
  int row = i >> 8, k4 = i & 255;
  int e = idx[row];
  float4 v = ((const float4*)emb)[(size_t)e * 256 + k4];
  ushort4 o; o.x = f2bf(v.x); o.y = f2bf(v.y); o.z = f2bf(v.z); o.w = f2bf(v.w);
  ((ushort4*)xe)[i] = o;
}

// ---------------- GEMM: C[M,N] = A[M,K] @ B[N,K]^T, bf16 in / fp32 out (X0 only) ----------------
__global__ __launch_bounds__(256) void gemm_bt(const u16* __restrict__ A, const u16* __restrict__ Bm,
                                               float* __restrict__ C, int M, int N, int K, int mtiles) {
  __shared__ u16 As[128 * 32];
  __shared__ u16 Bs[128 * 32];
  const int tid = threadIdx.x;
  const int bm = blockIdx.x % mtiles, bn = blockIdx.x / mtiles;
  const int m0 = bm * 128, n0 = bn * 128;
  const int lane = tid & 63, w = tid >> 6, wm = w & 1, wn = w >> 1;
  const int la = lane & 15, lk = lane >> 4;
  const int srow = tid >> 2, sk = (tid & 3) * 8;
  f32x4 acc[4][4] = {};
  for (int kt = 0; kt < K; kt += 32) {
    const u16* srcA0 = A + (size_t)(m0 + srow) * K + kt + sk;
    const u16* srcA1 = A + (size_t)(m0 + srow + 64) * K + kt + sk;
    const u16* srcB0 = Bm + (size_t)(n0 + srow) * K + kt + sk;
    const u16* srcB1 = Bm + (size_t)(n0 + srow + 64) * K + kt + sk;
    __builtin_amdgcn_global_load_lds((const __attribute__((address_space(1))) void*)srcA0,
        (__attribute__((address_space(3))) void*)((char*)As + tid * 16), 16, 0, 0);
    __builtin_amdgcn_global_load_lds((const __attribute__((address_space(1))) void*)srcA1,
        (__attribute__((address_space(3))) void*)((char*)As + 4096 + tid * 16), 16, 0, 0);
    __builtin_amdgcn_global_load_lds((const __attribute__((address_space(1))) void*)srcB0,
        (__attribute__((address_space(3))) void*)((char*)Bs + tid * 16), 16, 0, 0);
    __builtin_amdgcn_global_load_lds((const __attribute__((address_space(1))) void*)srcB1,
        (__attribute__((address_space(3))) void*)((char*)Bs + 4096 + tid * 16), 16, 0, 0);
    __syncthreads();
    bf16x8 av[4], bv[4];
    #pragma unroll
    for (int m = 0; m < 4; ++m)
      av[m] = *(const bf16x8*)(As + (wm * 64 + m * 16 + la) * 32 + lk * 8);
    #pragma unroll
    for (int n = 0; n < 4; ++n)
      bv[n] = *(const bf16x8*)(Bs + (wn * 64 + n * 16 + la) * 32 + lk * 8);
    #pragma unroll
    for (int m = 0; m < 4; ++m)
      #pragma unroll
      for (int n = 0; n < 4; ++n)
        acc[m][n] = __builtin_amdgcn_mfma_f32_16x16x32_bf16(av[m], bv[n], acc[m][n], 0, 0, 0);
    __syncthreads();
  }
  #pragma unroll
  for (int n = 0; n < 4; ++n) {
    const int gc = n0 + wn * 64 + n * 16 + la;
    #pragma unroll
    for (int m = 0; m < 4; ++m) {
      const int gr0 = m0 + wm * 64 + m * 16 + lk * 4;
      #pragma unroll
      for (int r = 0; r < 4; ++r)
        C[(size_t)(gr0 + r) * N + gc] = acc[m][n][r];
    }
  }
}

// ---------------- sync: per-phase ring counters ----------------
// Arrival: tid0 relaxed agent atomicAdd on a fresh word per phase. Wait: each wave's
// lane 0 polls the ONE dword until ==64, wave proceeds immediately.
// BUSY variant keeps the SIMD issuing a dependent FMA chain between polls instead of
// s_sleep -> waves look ACTIVE to the DVFS governor (H2: idle-spin downclock) and
// detection latency shrinks. Decoder blocks keep the s_sleep variant (BW-bound).

__device__ __forceinline__ void spinwork() {
  float x = 0.f;
  #pragma unroll
  for (int i = 0; i < 64; ++i)
    x = __builtin_fmaf(x, 1.0000001f, 1.0f);   // dependent chain ~256 cy, SIMD busy
  asm volatile("" :: "v"(x));
}

template<bool BUSY>
__device__ __forceinline__ void waitc1(const unsigned* wptr, unsigned need) {
  if (!need) return;
  unsigned g = 0;
  while (true) {
    unsigned v = need;
    if ((threadIdx.x & 63) == 0)
      asm volatile("global_load_dword %0, %1, off sc1\ns_waitcnt vmcnt(0)"
                   : "=v"(v) : "v"(wptr) : "memory");
    if (__all(v >= need)) break;
    if (BUSY) spinwork(); else __builtin_amdgcn_s_sleep(1);
    if (++g > (BUSY ? 200000u : 400000u)) break;   // hang guard (tens of ms)
  }
}

__device__ __forceinline__ void waitc2(const unsigned* w0, unsigned n0,
                                       const unsigned* w1, unsigned n1) {
  unsigned g = 0;
  while (true) {
    const int l = threadIdx.x & 63;
    bool ok = true;
    if (l < 2) {
      const unsigned* p = l ? w1 : w0;
      const unsigned need = l ? n1 : n0;
      unsigned v;
      asm volatile("global_load_dword %0, %1, off sc1\ns_waitcnt vmcnt(0)"
                   : "=v"(v) : "v"(p) : "memory");
      ok = (need == 0) || (v >= need);
    }
    if (__all(ok)) break;
    spinwork();
    if (++g > 200000u) break;
  }
}

__device__ __forceinline__ void arrivec(unsigned* wptr, int tid) {
  asm volatile("s_waitcnt vmcnt(0)" ::: "memory");   // per-wave: my sc1 stores at LLC
  __syncthreads();                                    // all waves drained
  if (tid == 0)
    __hip_atomic_fetch_add(wptr, 1u, __ATOMIC_RELAXED, __HIP_MEMORY_SCOPE_AGENT);
}

// non-temporal store: logits are write-once, never re-read -> don't evict decWb from LLC
__device__ __forceinline__ void store_nt(float* p, float v) {
  asm volatile("global_store_dword %0, %1, off nt" :: "v"(p), "v"(v) : "memory");
}

// ---------------- fused persistent kernel: recurrence + flag-chasing decoder ----------------
// Blocks 0..127: weight-stationary GRU recurrence. Blocks 128..252: decoder workers.
// Coherence: sc1 write-through stores; plain cached reads of write-once data strictly
// after counter; ONE agent-acquire fence at kernel entry (graph-replay staleness).

__global__ __launch_bounds__(256) void k_fused(
    const u16* __restrict__ hinitb,    // [2][64][1024] bf16 of initial hidden
    const float* __restrict__ hidden,  // [2][64][1024] fp32
    const float* __restrict__ X0,      // [64][64][3072] layer-0 x-projections
    const u16* __restrict__ Ucat0, const u16* __restrict__ Ucat1,  // [3072][1024] {Ur|Uz|Uh}
    const u16* __restrict__ Wcat1,                                  // [3072][1024] {Wx|Wz|Wh} layer1
    const float* __restrict__ br, const float* __restrict__ bz, const float* __restrict__ bh,
    u16* __restrict__ H0seq, u16* __restrict__ H1seq,  // [64][64][1024] bf16 hidden per step
    u16* __restrict__ RH0, u16* __restrict__ RH1,      // [64][64][1024] bf16 r*h per step
    const u16* __restrict__ decWb,     // [32000][1024] bf16 decoder weights
    const float* __restrict__ decb,    // [32000]
    float* __restrict__ out,           // logits [64*64][32000]; hfinal at out+SBV
    unsigned* cnt) {                   // ring counters: [2][132]
  extern __shared__ char sW[];        // 96KB (recurrence blocks): 3 x [16][1024] swizzled
  const int tid = threadIdx.x, bid = blockIdx.x;
  const int lane = tid & 63, w = tid >> 6;
  const int la = lane & 15, lk = lane >> 4;

  // drop stale L1/L2 lines from previous graph replay (ONCE per launch, all blocks)
  __builtin_amdgcn_fence(__ATOMIC_ACQUIRE, "agent");

  if (bid >= 128) {
    // ================= decoder worker =================
    const int d = bid - 128;          // 0..124
    const int c0 = d * 256 + w * 64;  // wave's 64-col strip
    const unsigned* cL1 = cnt + 132;
    float bb[4];
    #pragma unroll
    for (int nf = 0; nf < 4; ++nf) bb[nf] = decb[c0 + nf * 16 + la];
    const u16* Bp[4];
    #pragma unroll
    for (int nf = 0; nf < 4; ++nf)
      Bp[nf] = decWb + (size_t)(c0 + nf * 16 + la) * 1024 + lk * 8;
    for (int t = 0; t < 64; ++t) {
      waitc1<false>(cL1 + 2 * t + 2, 64u);     // H1seq[t] complete
      const u16* Ab = H1seq + (size_t)t * 65536;
      const u16* Ap[4];
      #pragma unroll
      for (int mf = 0; mf < 4; ++mf) Ap[mf] = Ab + (mf * 16 + la) * 1024 + lk * 8;
      f32x4 acc[4][4] = {};
      #pragma unroll 4
      for (int ks = 0; ks < 32; ++ks) {
        bf16x8 av[4], bv[4];
        #pragma unroll
        for (int mf = 0; mf < 4; ++mf) av[mf] = *(const bf16x8*)(Ap[mf] + ks * 32);
        #pragma unroll
        for (int nf = 0; nf < 4; ++nf) bv[nf] = *(const bf16x8*)(Bp[nf] + ks * 32);
        #pragma unroll
        for (int mf = 0; mf < 4; ++mf)
          #pragma unroll
          for (int nf = 0; nf < 4; ++nf)
            acc[mf][nf] = __builtin_amdgcn_mfma_f32_16x16x32_bf16(av[mf], bv[nf], acc[mf][nf], 0, 0, 0);
      }
      #pragma unroll
      for (int mf = 0; mf < 4; ++mf)
        #pragma unroll
        for (int nf = 0; nf < 4; ++nf) {
          const size_t rb = (size_t)(t * 64 + mf * 16 + lk * 4) * 32000 + c0 + nf * 16 + la;
          #pragma unroll
          for (int r = 0; r < 4; ++r)
            store_nt(out + rb + (size_t)r * 32000, acc[mf][nf][r] + bb[nf]);
        }
    }
    return;
  }

  // ================= recurrence block =================
  const int layer = bid >> 6, jb = bid & 63, j0 = jb * 16;
  const int jl = j0 + la;             // this lane's output col (C/D: col = lane&15)
  const int row0 = w * 16;            // wave's 16 batch rows
  const u16* Ucat = layer ? Ucat1 : Ucat0;
  u16* Hseq = layer ? H1seq : H0seq;
  u16* RHl = layer ? RH1 : RH0;
  const u16* hinit = hinitb + layer * 65536;
  unsigned* cSelf = cnt + layer * 132;
  const unsigned* cL0 = cnt;
  float* houtf = out + (size_t)SBV;

  // ---- stage U weight slice into LDS (once): 6144 16B-chunks / 256 thr = 24 each ----
  const int xorv = (la & 7) << 4;
  for (int i = 0; i < 24; ++i) {
    int c = i * 256 + tid;                       // 0..6143
    int g = c >> 11, rem = c & 2047;             // 2048 chunks per gate
    int urow = rem >> 7, kc = rem & 127;
    uint4 v = *(const uint4*)(Ucat + ((size_t)((g << 10) + j0 + urow)) * 1024 + kc * 8);
    *(uint4*)(sW + (g << 15) + urow * 2048 + ((kc * 16) ^ ((urow & 7) << 4))) = v;
  }
  __syncthreads();
  const char* sWla = sW + la * 2048;             // per-lane weight row base

  float h_reg[4], z_reg[4];
  #pragma unroll
  for (int r = 0; r < 4; ++r)
    h_reg[r] = hidden[layer * 65536 + (row0 + lk * 4 + r) * 1024 + jl];
  const float bR = br[layer * 1024 + jl], bZ = bz[layer * 1024 + jl], bH = bh[layer * 1024 + jl];

  // L1 W-stream row bases (B-operand: row = col j0+la), plain loads -> L2-resident slice
  const u16* WrR = Wcat1 + (size_t)(j0 + la) * 1024 + lk * 8;
  const u16* WrZ = WrR + (size_t)1024 * 1024;
  const u16* WrH = WrR + (size_t)2048 * 1024;

  for (int t = 0; t < 64; ++t) {
    // ================= phase A: r,z gates =================
    if (layer == 0) waitc1<true>(cSelf + 2 * t, t ? 64u : 0u);
    else            waitc2(cSelf + 2 * t, t ? 64u : 0u, cL0 + 2 * t + 2, 64u);
    const u16* hsrc = (t == 0) ? hinit : (Hseq + (size_t)(t - 1) * 65536);
    const u16* ap = hsrc + (size_t)(row0 + la) * 1024 + lk * 8;
    f32x4 accR = {0.f, 0.f, 0.f, 0.f}, accZ = {0.f, 0.f, 0.f, 0.f};
    if (layer == 0) {
      #pragma unroll 16
      for (int ks = 0; ks < 32; ++ks) {
        const int kx = (ks * 64 + lk * 16) ^ xorv;
        bf16x8 a = *(const bf16x8*)(ap + ks * 32);
        accR = __builtin_amdgcn_mfma_f32_16x16x32_bf16(a, *(const bf16x8*)(sWla + kx), accR, 0, 0, 0);
        accZ = __builtin_amdgcn_mfma_f32_16x16x32_bf16(a, *(const bf16x8*)(sWla + 32768 + kx), accZ, 0, 0, 0);
      }
    } else {
      const u16* xp = H0seq + (size_t)t * 65536 + (size_t)(row0 + la) * 1024 + lk * 8;
      #pragma unroll 8
      for (int ks = 0; ks < 32; ++ks) {
        const int kx = (ks * 64 + lk * 16) ^ xorv;
        bf16x8 a = *(const bf16x8*)(ap + ks * 32);
        bf16x8 x = *(const bf16x8*)(xp + ks * 32);
        accR = __builtin_amdgcn_mfma_f32_16x16x32_bf16(a, *(const bf16x8*)(sWla + kx), accR, 0, 0, 0);
        accZ = __builtin_amdgcn_mfma_f32_16x16x32_bf16(a, *(const bf16x8*)(sWla + 32768 + kx), accZ, 0, 0, 0);
        accR = __builtin_amdgcn_mfma_f32_16x16x32_bf16(x, *(const bf16x8*)(WrR + ks * 32), accR, 0, 0, 0);
        accZ = __builtin_amdgcn_mfma_f32_16x16x32_bf16(x, *(const bf16x8*)(WrZ + ks * 32), accZ, 0, 0, 0);
      }
    }
    #pragma unroll
    for (int r = 0; r < 4; ++r) {
      const int row = row0 + lk * 4 + r;  // C/D: row = (lane>>4)*4 + reg
      float pr = accR[r] + bR, pz = accZ[r] + bZ;
      if (layer == 0) {
        const float* xf = X0 + (size_t)(t * 64 + row) * 3072 + jl;
        pr += xf[0]; pz += xf[1024];
      }
      float rv = sigm(pr);
      z_reg[r] = sigm(pz);
      unsigned v = f2bf(rv * h_reg[r]);
      u16* p = RHl + (size_t)(t * 64 + row) * 1024 + jl;
      asm volatile("global_store_short %0, %1, off sc1" :: "v"(p), "v"(v));
    }
    arrivec(cSelf + 2 * t + 1, tid);
    // ================= phase B: candidate + state update =================
    waitc1<true>(cSelf + 2 * t + 1, 64u);
    const u16* rp = RHl + (size_t)t * 65536 + (size_t)(row0 + la) * 1024 + lk * 8;
    f32x4 accH = {0.f, 0.f, 0.f, 0.f};
    if (layer == 0) {
      #pragma unroll 16
      for (int ks = 0; ks < 32; ++ks) {
        const int kx = (ks * 64 + lk * 16) ^ xorv;
        bf16x8 a = *(const bf16x8*)(rp + ks * 32);
        accH = __builtin_amdgcn_mfma_f32_16x16x32_bf16(a, *(const bf16x8*)(sWla + 65536 + kx), accH, 0, 0, 0);
      }
    } else {
      const u16* xp = H0seq + (size_t)t * 65536 + (size_t)(row0 + la) * 1024 + lk * 8;
      #pragma unroll 8
      for (int ks = 0; ks < 32; ++ks) {
        const int kx = (ks * 64 + lk * 16) ^ xorv;
        bf16x8 a = *(const bf16x8*)(rp + ks * 32);
        bf16x8 x = *(const bf16x8*)(xp + ks * 32);
        accH = __builtin_amdgcn_mfma_f32_16x16x32_bf16(a, *(const bf16x8*)(sWla + 65536 + kx), accH, 0, 0, 0);
        accH = __builtin_amdgcn_mfma_f32_16x16x32_bf16(x, *(const bf16x8*)(WrH + ks * 32), accH, 0, 0, 0);
      }
    }
    #pragma unroll
    for (int r = 0; r < 4; ++r) {
      const int row = row0 + lk * 4 + r;
      float pre = accH[r] + bH;
      if (layer == 0) pre += X0[(size_t)(t * 64 + row) * 3072 + 2048 + jl];
      float hc = tanh_f(pre);
      float hn = h_reg[r] + z_reg[r] * (hc - h_reg[r]);  // (1-z)h + z*hcand
      h_reg[r] = hn;
      unsigned v = f2bf(hn);
      u16* p = Hseq + (size_t)(t * 64 + row) * 1024 + jl;
      asm volatile("global_store_short %0, %1, off sc1" :: "v"(p), "v"(v));
      if (t == 63) houtf[layer * 65536 + row * 1024 + jl] = hn;
    }
    arrivec(cSelf + 2 * t + 2, tid);
  }
}

// ---------------- host launch ----------------
extern "C" void kernel_launch(void* const* d_in, const int* in_sizes, int n_in,
                              void* d_out, int out_size, void* d_ws, size_t ws_size,
                              hipStream_t stream) {
  const int* inputs = (const int*)d_in[0];
  const float* hidden = (const float*)d_in[1];
  const float* emb = (const float*)d_in[2];
  const float* Wx = (const float*)d_in[3];
  const float* Ur = (const float*)d_in[4];
  const float* br = (const float*)d_in[5];
  const float* Wz = (const float*)d_in[6];
  const float* Uz = (const float*)d_in[7];
  const float* bz = (const float*)d_in[8];
  const float* Wh = (const float*)d_in[9];
  const float* Uh = (const float*)d_in[10];
  const float* bh = (const float*)d_in[11];
  const float* decW = (const float*)d_in[12];
  const float* decb = (const float*)d_in[13];
  float* out = (float*)d_out;

  char* ws = (char*)d_ws;
  size_t off = 0;
  auto alloc = [&](size_t bytes) { char* p = ws + off; off += (bytes + 255) & ~(size_t)255; return p; };
  unsigned* cnt = (unsigned*)alloc(4096);     // ring counters [2][132]
  u16* hinitb = (u16*)alloc((size_t)2 * 64 * 1024 * 2);
  u16* xe     = (u16*)alloc((size_t)4096 * 1024 * 2);
  u16* Wcat0b = (u16*)alloc((size_t)3072 * 1024 * 2);
  u16* Wcat1b = (u16*)alloc((size_t)3072 * 1024 * 2);
  u16* Ucat0b = (u16*)alloc((size_t)3072 * 1024 * 2);
  u16* Ucat1b = (u16*)alloc((size_t)3072 * 1024 * 2);
  u16* decWb  = (u16*)alloc((size_t)32000 * 1024 * 2);
  float* X0   = (float*)alloc((size_t)4096 * 3072 * 4);
  u16* H0seq  = (u16*)alloc((size_t)4096 * 1024 * 2);
  u16* H1seq  = (u16*)alloc((size_t)4096 * 1024 * 2);
  u16* RH0    = (u16*)alloc((size_t)4096 * 1024 * 2);
  u16* RH1    = (u16*)alloc((size_t)4096 * 1024 * 2);

  hipMemsetAsync(cnt, 0, 4096, stream);
  k_cvtv<<<128, 256, 0, stream>>>(hidden, hinitb, 32768);
  k_pack3<<<3072, 256, 0, stream>>>(Wx, Wz, Wh, 0, Wcat0b);
  k_pack3<<<3072, 256, 0, stream>>>(Wx, Wz, Wh, 1048576, Wcat1b);
  k_pack3<<<3072, 256, 0, stream>>>(Ur, Uz, Uh, 0, Ucat0b);
  k_pack3<<<3072, 256, 0, stream>>>(Ur, Uz, Uh, 1048576, Ucat1b);
  k_embed<<<4096, 256, 0, stream>>>(inputs, emb, xe);
  k_cvtv<<<4096, 256, 0, stream>>>(decW, decWb, 8192000);

  // layer-0 x-projections for all timesteps: [4096,1024] @ [3072,1024]^T
  gemm_bt<<<768, 256, 0, stream>>>(xe, Wcat0b, X0, 4096, 3072, 1024, 32);

  // fused: weight-stationary recurrence (blocks 0..127) + flag-chasing decoder (128..252)
  (void)hipFuncSetAttribute(reinterpret_cast<const void*>(&k_fused),
                            hipFuncAttributeMaxDynamicSharedMemorySize, 98304);
  k_fused<<<253, 256, 98304, stream>>>(hinitb, hidden, X0, Ucat0b, Ucat1b, Wcat1b,
                                       br, bz, bh, H0seq, H1seq, RH0, RH1,
                                       decWb, decb, out, cnt);
}